// Round 3
// baseline (626.099 us; speedup 1.0000x reference)
//
#include <hip/hip_runtime.h>
#include <math.h>

// ---- problem constants (fixed by reference) ----
#define B_SZ 512
#define D_SZ 256
#define C_SZ 100000
#define S_SCALE 30.0f
#define COS_Mc 0.8775825618903728f        // cos(0.5)
#define SIN_Mc 0.479425538604203f         // sin(0.5)
#define THRESHOLDc (-0.8775825618903728f) // cos(pi-0.5)
#define MMc 0.2397127693021015f           // sin(pi-0.5)*0.5
#define EPSc 1e-12f

// d_out layout (floats): [logits B*C][new_weight C*D][t_new 1]
#define OUT_W_OFF ((size_t)B_SZ * C_SZ)             // 51,200,000
#define OUT_T_OFF (OUT_W_OFF + (size_t)C_SZ * D_SZ) // 76,800,000

// ws layout (floats)
#define WS_F 0                  // f normalized [B,D] fp32
#define WS_TL (B_SZ * D_SZ)     // target_logit [B]
#define WS_CTM (WS_TL + B_SZ)   // cos_theta_m [B]
#define WS_FLT (WS_CTM + B_SZ)  // final_target_logit [B]
#define WS_TNEW (WS_FLT + B_SZ) // t_new [1]

typedef __attribute__((ext_vector_type(8))) short bf16x8; // MFMA A/B frag (4 VGPRs)
typedef __attribute__((ext_vector_type(4))) short s16x4;
typedef __attribute__((ext_vector_type(4))) float f32x4;  // MFMA C/D frag

__device__ __forceinline__ float wave_reduce_sum(float v) {
#pragma unroll
    for (int off = 32; off > 0; off >>= 1) v += __shfl_down(v, off, 64);
    return v;
}

__device__ __forceinline__ short f2bf(float x) { // RNE fp32->bf16
    union { float f; unsigned u; } v; v.f = x;
    unsigned r = v.u + 0x7fff + ((v.u >> 16) & 1);
    return (short)(r >> 16);
}
__device__ __forceinline__ float bf2f(short h) {
    union { float f; unsigned u; } v;
    v.u = ((unsigned)(unsigned short)h) << 16;
    return v.f;
}

// One block per batch row: normalize, target dot, per-row margin scalars.
__global__ __launch_bounds__(256) void prep_kernel(
    const float* __restrict__ features, const int* __restrict__ targets,
    const float* __restrict__ weight, float* __restrict__ f,
    float* __restrict__ tl, float* __restrict__ ctm, float* __restrict__ flt) {
    int b = blockIdx.x;
    int d = threadIdx.x;
    float x = features[b * D_SZ + d];
    float v = wave_reduce_sum(x * x);
    __shared__ float red[4];
    int wave = d >> 6, lane = d & 63;
    if (lane == 0) red[wave] = v;
    __syncthreads();
    float s = red[0] + red[1] + red[2] + red[3];
    float scale = 1.0f / fmaxf(sqrtf(s), EPSc);
    float fv = x * scale;
    f[b * D_SZ + d] = fv;

    int tgt = targets[b];
    float wv = weight[(size_t)tgt * D_SZ + d];
    float p = wave_reduce_sum(fv * wv);
    __syncthreads();
    if (lane == 0) red[wave] = p;
    __syncthreads();
    if (d == 0) {
        float t_l = red[0] + red[1] + red[2] + red[3];
        tl[b] = t_l;
        float sin_t = sqrtf(fmaxf(1.0f - t_l * t_l, 0.0f));
        float c_m = t_l * COS_Mc - sin_t * SIN_Mc;
        ctm[b] = c_m;
        flt[b] = (t_l > THRESHOLDc) ? c_m : (t_l - MMc);
    }
}

// One block: t_new = mean(tl)*0.01 + 0.99*t
__global__ __launch_bounds__(512) void tnew_kernel(
    const float* __restrict__ tl, const float* __restrict__ t_in,
    float* __restrict__ tnew_ws, float* __restrict__ out_t) {
    int i = threadIdx.x;
    float v = wave_reduce_sum(tl[i]);
    __shared__ float red[8];
    int wave = i >> 6, lane = i & 63;
    if (lane == 0) red[wave] = v;
    __syncthreads();
    if (i == 0) {
        float s = 0.f;
#pragma unroll
        for (int w = 0; w < 8; w++) s += red[w];
        float tn = (s / (float)B_SZ) * 0.01f + 0.99f * t_in[0];
        tnew_ws[0] = tn;
        out_t[0] = tn;
    }
}

// Split-precision bf16 MFMA GEMM: cos = f @ W^T with fused ArcFace epilogue.
// BM=BN=128, BK=32, 4 waves in 2x2, 64x64 per wave (4x4 frags of 16x16x32).
#define BMt 128
#define BNt 128
#define LDK 40 // 32 k-shorts + 8 pad -> 80B row stride (16B aligned, 2-way banks)

__global__ __launch_bounds__(256) void gemm_kernel(
    const float* __restrict__ f, const float* __restrict__ weight,
    const int* __restrict__ targets, const float* __restrict__ ctm,
    const float* __restrict__ flt, const float* __restrict__ tnew,
    float* __restrict__ out) {
    __shared__ short As_hi[BMt][LDK];
    __shared__ short As_lo[BMt][LDK];
    __shared__ short Bs_hi[BNt][LDK];
    __shared__ short Bs_lo[BNt][LDK];

    const int t = threadIdx.x;
    const int row0 = blockIdx.y * BMt;
    const int col0 = blockIdx.x * BNt;
    const int w = t >> 6, lane = t & 63;
    const int wr = w >> 1, wc = w & 1; // 2x2 wave grid
    const int fr = lane & 15;          // frag row (A) / col (B) / col (D)
    const int kg = (lane >> 4) * 8;    // frag k-offset (elements)

    f32x4 acc[4][4] = {};

    for (int kt = 0; kt < D_SZ; kt += 32) {
#pragma unroll
        for (int i = 0; i < 4; i++) {
            int flat = i * 256 + t;  // 0..1023
            int m = flat >> 3;       // 0..127
            int kq = flat & 7;       // float4 within the 32-k chunk
            // A tile (f rows, always valid: B=512 = 4*128)
            float4 va = *(const float4*)&f[(row0 + m) * D_SZ + kt + kq * 4];
            s16x4 h, l;
            h.x = f2bf(va.x); l.x = f2bf(va.x - bf2f(h.x));
            h.y = f2bf(va.y); l.y = f2bf(va.y - bf2f(h.y));
            h.z = f2bf(va.z); l.z = f2bf(va.z - bf2f(h.z));
            h.w = f2bf(va.w); l.w = f2bf(va.w - bf2f(h.w));
            *(s16x4*)&As_hi[m][kq * 4] = h;
            *(s16x4*)&As_lo[m][kq * 4] = l;
            // B tile (weight rows, guard last N-tile)
            int c = col0 + m;
            float4 vb = make_float4(0.f, 0.f, 0.f, 0.f);
            if (c < C_SZ) vb = *(const float4*)&weight[(size_t)c * D_SZ + kt + kq * 4];
            h.x = f2bf(vb.x); l.x = f2bf(vb.x - bf2f(h.x));
            h.y = f2bf(vb.y); l.y = f2bf(vb.y - bf2f(h.y));
            h.z = f2bf(vb.z); l.z = f2bf(vb.z - bf2f(h.z));
            h.w = f2bf(vb.w); l.w = f2bf(vb.w - bf2f(h.w));
            *(s16x4*)&Bs_hi[m][kq * 4] = h;
            *(s16x4*)&Bs_lo[m][kq * 4] = l;
        }
        __syncthreads();

        bf16x8 ah[4], al[4], bh[4], bl[4];
#pragma unroll
        for (int mi = 0; mi < 4; mi++) {
            int m = wr * 64 + mi * 16 + fr;
            ah[mi] = *(const bf16x8*)&As_hi[m][kg];
            al[mi] = *(const bf16x8*)&As_lo[m][kg];
        }
#pragma unroll
        for (int ni = 0; ni < 4; ni++) {
            int c = wc * 64 + ni * 16 + fr;
            bh[ni] = *(const bf16x8*)&Bs_hi[c][kg];
            bl[ni] = *(const bf16x8*)&Bs_lo[c][kg];
        }
#pragma unroll
        for (int mi = 0; mi < 4; mi++)
#pragma unroll
            for (int ni = 0; ni < 4; ni++) {
                acc[mi][ni] = __builtin_amdgcn_mfma_f32_16x16x32_bf16(
                    ah[mi], bh[ni], acc[mi][ni], 0, 0, 0);
                acc[mi][ni] = __builtin_amdgcn_mfma_f32_16x16x32_bf16(
                    ah[mi], bl[ni], acc[mi][ni], 0, 0, 0);
                acc[mi][ni] = __builtin_amdgcn_mfma_f32_16x16x32_bf16(
                    al[mi], bh[ni], acc[mi][ni], 0, 0, 0);
            }
        __syncthreads();
    }

    // fused ArcFace epilogue; D frag: col = lane&15, row = (lane>>4)*4 + reg
    float tn = tnew[0];
#pragma unroll
    for (int mi = 0; mi < 4; mi++) {
#pragma unroll
        for (int j = 0; j < 4; j++) {
            int r = row0 + wr * 64 + mi * 16 + (lane >> 4) * 4 + j;
            int tg = targets[r];
            float cm = ctm[r], fl = flt[r];
            size_t base = (size_t)r * C_SZ;
#pragma unroll
            for (int ni = 0; ni < 4; ni++) {
                int c = col0 + wc * 64 + ni * 16 + fr;
                if (c < C_SZ) {
                    float v = acc[mi][ni][j];
                    if (c == tg) v = fl;
                    else if (v > cm) v = v * (tn + v);
                    out[base + c] = v * S_SCALE;
                }
            }
        }
    }
}

// bulk copy weight -> out new_weight region
__global__ __launch_bounds__(256) void copyw_kernel(
    const float4* __restrict__ src, float4* __restrict__ dst, int n4) {
    int i = blockIdx.x * blockDim.x + threadIdx.x;
    if (i < n4) dst[i] = src[i];
}

// per-unique-target EMA weight update (overwrites touched rows)
__global__ __launch_bounds__(256) void updw_kernel(
    const int* __restrict__ targets, const float* __restrict__ f,
    const float* __restrict__ weight, float* __restrict__ outw) {
    int b = blockIdx.x;
    int c = targets[b];
    for (int i = 0; i < b; i++)
        if (targets[i] == c) return; // block-uniform early exit
    int d = threadIdx.x;
    float sum = 0.f;
    int cnt = 0;
    for (int i = b; i < B_SZ; i++) {
        if (targets[i] == c) { sum += f[i * D_SZ + d]; cnt++; }
    }
    float mean = sum / (float)cnt;
    float upd = 0.5f * weight[(size_t)c * D_SZ + d] + 0.5f * mean;
    float v = wave_reduce_sum(upd * upd);
    __shared__ float red[4];
    int wave = d >> 6, lane = d & 63;
    if (lane == 0) red[wave] = v;
    __syncthreads();
    float s = red[0] + red[1] + red[2] + red[3];
    float nrm = fmaxf(sqrtf(s), EPSc);
    outw[(size_t)c * D_SZ + d] = upd / nrm;
}

extern "C" void kernel_launch(void* const* d_in, const int* in_sizes, int n_in,
                              void* d_out, int out_size, void* d_ws, size_t ws_size,
                              hipStream_t stream) {
    const float* features = (const float*)d_in[0];
    const int* targets = (const int*)d_in[1];
    const float* weight = (const float*)d_in[2];
    const float* t_in = (const float*)d_in[3];
    float* out = (float*)d_out;
    float* ws = (float*)d_ws;

    float* f = ws + WS_F;
    float* tl = ws + WS_TL;
    float* ctm = ws + WS_CTM;
    float* flt = ws + WS_FLT;
    float* tnew = ws + WS_TNEW;

    prep_kernel<<<B_SZ, 256, 0, stream>>>(features, targets, weight, f, tl, ctm, flt);
    tnew_kernel<<<1, 512, 0, stream>>>(tl, t_in, tnew, out + OUT_T_OFF);

    int n4 = (C_SZ * D_SZ) / 4;
    copyw_kernel<<<(n4 + 255) / 256, 256, 0, stream>>>(
        (const float4*)weight, (float4*)(out + OUT_W_OFF), n4);

    dim3 ggrid((C_SZ + BNt - 1) / BNt, B_SZ / BMt); // 782 x 4
    gemm_kernel<<<ggrid, 256, 0, stream>>>(f, weight, targets, ctm, flt, tnew, out);

    updw_kernel<<<B_SZ, 256, 0, stream>>>(targets, f, weight, out + OUT_W_OFF);
}